// Round 16
// baseline (94.957 us; speedup 1.0000x reference)
//
#include <hip/hip_runtime.h>

// NestedConv via MFMA bf16: B=64, N=128, D=64.
// out[b,i,j,:] = m[b,i,j] * sum_k A[b,k,j] * h[b,i,k,:]
// h = relu(relu((m*X)@W1+b1)@W2+b2),  A symmetric 0/1 (bf16-exact).
//
// Round-16 = Round-15 with ONE change: all hot-path inline-asm
// v_cvt_pk_bf16_f32 replaced by schedulable bit-op f2bf (m240: asm cvt_pk
// -37% vs scalar cast — asm pins regs and blocks the scheduler). Keeps R15's
// vector back-end: swapped L1 (uint2 H1 writes), swapped P2 (f32x4 NT
// stores), staged coalesced X front-end, X-skip, minimal barriers.
#define Bv 64
#define Nv 128
#define Dv 64

// ws layout (bytes): [0,16K) wpk; [20480] flag; [32K, 32K+2M) apk.
#define FLAG_OFF_B 20480
#define APK_OFF_B  32768
#define WS_NEED (32768 + Bv * 32768)

typedef __attribute__((ext_vector_type(8))) short bf16x8;
typedef __attribute__((ext_vector_type(4))) float f32x4;

// f32 -> bf16 RNE, pure bit ops (schedulable; compiler interleaves freely)
__device__ __forceinline__ unsigned short f2bf(float f) {
    unsigned u = __float_as_uint(f);
    u += 0x7FFFu + ((u >> 16) & 1u);
    return (unsigned short)(u >> 16);
}
__device__ __forceinline__ unsigned pk2(float a, float b) {
    return (unsigned)f2bf(a) | ((unsigned)f2bf(b) << 16);
}
__device__ __forceinline__ bf16x8 pack8m(float4 a, float4 b, float m) {
    bf16x8 r;
    r[0] = (short)f2bf(m * a.x); r[1] = (short)f2bf(m * a.y);
    r[2] = (short)f2bf(m * a.z); r[3] = (short)f2bf(m * a.w);
    r[4] = (short)f2bf(m * b.x); r[5] = (short)f2bf(m * b.y);
    r[6] = (short)f2bf(m * b.z); r[7] = (short)f2bf(m * b.w);
    return r;
}
__device__ __forceinline__ bf16x8 pack8(float4 a, float4 b) {
    return pack8m(a, b, 1.0f);
}
// relu + pack 4 accumulator floats -> 8B (bit ops, schedulable)
__device__ __forceinline__ uint2 relu_pk4(f32x4 v) {
    return make_uint2(pk2(fmaxf(v[0], 0.f), fmaxf(v[1], 0.f)),
                      pk2(fmaxf(v[2], 0.f), fmaxf(v[3], 0.f)));
}
// XOR-swizzled byte address in a row-major LDS tile with 128 B rows
__device__ __forceinline__ int swz128(int r, int bo) {
    return r * 128 + (((bo & ~15) ^ ((r & 7) << 4)) | (bo & 15));
}
// fallback W fragment loader (PRE=false only)
__device__ __forceinline__ bf16x8 load_w_frag(const float* __restrict__ W,
                                              int kkbase, int dn, int l15, int l16) {
    const float* p = W + (kkbase + 8 * l16) * Dv + dn + l15;
    bf16x8 r;
    #pragma unroll
    for (int t = 0; t < 8; ++t) r[t] = (short)f2bf(p[t * Dv]);
    return r;
}

// ---- pre-kernel: pack W1,W2 fragments ----
// Wpk[f][l][t], f = layer*8 + kk*4 + tn; value = W[kk*32+8*(l>>4)+t][tn*16+(l&15)]
__global__ void pack_w_kernel(const float* __restrict__ W1,
                              const float* __restrict__ W2,
                              unsigned short* __restrict__ wpk) {
    const int idx = blockIdx.x * 256 + threadIdx.x;   // 1024 items
    const int l = idx & 63, f = idx >> 6;             // f = 0..15
    const int layer = f >> 3, kk = (f >> 2) & 1, tn = f & 3;
    const float* W = layer ? W2 : W1;
    const float* p = W + (kk * 32 + 8 * (l >> 4)) * Dv + tn * 16 + (l & 15);
    unsigned short* o = wpk + f * 512 + l * 8;
    #pragma unroll
    for (int t = 0; t < 8; ++t) o[t] = f2bf(p[t * Dv]);
}

// ---- pre-kernel: pack A fragments ----
// Apk[b][jt][kk][l][t] = A[b][jt*16+(l&15)][kk*32+8*(l>>4)+t]
__global__ void pack_a_kernel(const float* __restrict__ A,
                              unsigned short* __restrict__ apk) {
    const int gid = blockIdx.x * 256 + threadIdx.x;   // 131072 items
    const int l = gid & 63, f = gid >> 6;             // f = b*32 + jt*4 + kk
    const int b = f >> 5, r = f & 31, jt = r >> 2, kk = r & 3;
    const float4* p = (const float4*)(A +
        ((size_t)(b * Nv + jt * 16 + (l & 15))) * Nv + kk * 32 + 8 * (l >> 4));
    *(bf16x8*)(apk + (size_t)f * 512 + l * 8) = pack8(p[0], p[1]);
}

// ---- pre-kernel: flag = 1 iff all biases are exactly zero ----
__global__ void check_bias(const float* __restrict__ b1,
                           const float* __restrict__ b2,
                           int* __restrict__ flag) {
    __shared__ int nz;
    if (threadIdx.x == 0) nz = 0;
    __syncthreads();
    const float v = (threadIdx.x < 64) ? b1[threadIdx.x] : b2[threadIdx.x - 64];
    if (v != 0.0f) atomicOr(&nz, 1);
    __syncthreads();
    if (threadIdx.x == 0) flag[0] = (nz == 0) ? 1 : 0;
}

template <bool PRE>
__global__ __launch_bounds__(256, 3)
void nested_conv_mfma(const float* __restrict__ X,
                      const float* __restrict__ A,
                      const int*   __restrict__ mask,
                      const float* __restrict__ W1,
                      const float* __restrict__ b1,
                      const float* __restrict__ W2,
                      const float* __restrict__ b2,
                      const unsigned short* __restrict__ wpk,
                      const unsigned short* __restrict__ apk,
                      const int*   __restrict__ bzflag,
                      float* __restrict__ out)
{
    // One 16 KB buffer, reused: Xs[128][64] -> H1[128][64] -> H2T[64][128] (bf16, swizzled)
    __shared__ __align__(16) unsigned char Sb[16384];

    const int i = blockIdx.x, b = blockIdx.y;
    const int tid = threadIdx.x;
    const int l   = tid & 63;
    const int w   = tid >> 6;       // wave 0..3
    const int l15 = l & 15;
    const int l16 = l >> 4;

    const size_t bi = (size_t)(b * Nv + i);
    const int flz = PRE ? bzflag[0] : 0;   // 1 => biases zero => masked rows' X dead

    // ---- stage masked X as bf16 into Xs[r][d] (coalesced; wave-banded rows) ----
    {
        const int sr = tid >> 1;              // row 32w + (l>>1): own wave's band
        const int sh = (tid & 1) << 5;        // d offset 0 or 32
        const float mm = mask[bi * Nv + sr] ? 1.0f : 0.0f;
        const float4* xp = (const float4*)(X + (bi * Nv + sr) * Dv + sh);
        if (!flz || mm != 0.0f) {
            #pragma unroll
            for (int g = 0; g < 4; ++g)
                *(bf16x8*)&Sb[swz128(sr, 2 * sh + 16 * g)] =
                    pack8m(xp[2 * g], xp[2 * g + 1], mm);
        } else {
            const bf16x8 z = {0, 0, 0, 0, 0, 0, 0, 0};
            #pragma unroll
            for (int g = 0; g < 4; ++g)
                *(bf16x8*)&Sb[swz128(sr, 2 * sh + 16 * g)] = z;
        }
    }
    // no barrier: staging rows, L1 reads, H1 writes, h1f reads all in wave band
    // (same-wave LDS W->R is issue-ordered; proven in R5/R14/R15)

    // ===== L1 (swapped): H1T-tile = mfma(W1T-frag, XmT-frag) =====
    // xf = SAME LDS fragment bytes as the non-swapped A-operand (layouts coincide)
    bf16x8 xf[2][2];   // [rr][kk]
    #pragma unroll
    for (int rr = 0; rr < 2; ++rr)
        #pragma unroll
        for (int kk = 0; kk < 2; ++kk) {
            const int r = (2 * w + rr) * 16 + l15;
            xf[rr][kk] = *(const bf16x8*)&Sb[r * 128 + ((kk * 64 + 16 * l16) ^ ((r & 7) << 4))];
        }
    f32x4 acc[2][4];
    #pragma unroll
    for (int dt = 0; dt < 4; ++dt) {   // C rows = d: init b1[dt*16 + 4*l16 + e]
        const float4 bv = *(const float4*)&b1[dt * 16 + 4 * l16];
        acc[0][dt] = (f32x4){bv.x, bv.y, bv.z, bv.w};
        acc[1][dt] = acc[0][dt];
    }
    #pragma unroll
    for (int kk = 0; kk < 2; ++kk)
        #pragma unroll
        for (int dt = 0; dt < 4; ++dt) {
            const bf16x8 wf = PRE
                ? *(const bf16x8*)(wpk + (kk * 4 + dt) * 512 + l * 8)
                : load_w_frag(W1, kk * 32, dt * 16, l15, l16);
            acc[0][dt] = __builtin_amdgcn_mfma_f32_16x16x32_bf16(wf, xf[0][kk], acc[0][dt], 0, 0, 0);
            acc[1][dt] = __builtin_amdgcn_mfma_f32_16x16x32_bf16(wf, xf[1][kk], acc[1][dt], 0, 0, 0);
        }
    // H1[r][d] vector writes: r = (2w+rr)*16+l15, d = dt*16+4*l16+reg -> one 8B write
    #pragma unroll
    for (int rr = 0; rr < 2; ++rr) {
        const int r = (2 * w + rr) * 16 + l15;
        #pragma unroll
        for (int dt = 0; dt < 4; ++dt) {
            const int bo = dt * 32 + l16 * 8;
            *(uint2*)&Sb[swz128(r, bo)] = relu_pk4(acc[rr][dt]);
        }
    }

    // hoist H1 fragment reads (wave-banded) before the WAR barrier
    bf16x8 h1f[2][2];
    #pragma unroll
    for (int kk = 0; kk < 2; ++kk)
        #pragma unroll
        for (int rr = 0; rr < 2; ++rr) {
            const int r = (2 * w + rr) * 16 + l15;
            h1f[kk][rr] = *(const bf16x8*)&Sb[r * 128 + ((kk * 64 + 16 * l16) ^ ((r & 7) << 4))];
        }
    __syncthreads();   // barrier #1: all h1f in registers; H2T may now clobber Sb

    // ===== L2 (normal): H2 = relu(H1 @ W2 + b2) =====
    f32x4 acc2[2][4];
    #pragma unroll
    for (int tn = 0; tn < 4; ++tn) {
        const float bv = b2[tn * 16 + l15];
        acc2[0][tn] = (f32x4){bv, bv, bv, bv};
        acc2[1][tn] = acc2[0][tn];
    }
    #pragma unroll
    for (int kk = 0; kk < 2; ++kk)
        #pragma unroll
        for (int tn = 0; tn < 4; ++tn) {
            const bf16x8 wf = PRE
                ? *(const bf16x8*)(wpk + (8 + kk * 4 + tn) * 512 + l * 8)
                : load_w_frag(W2, kk * 32, tn * 16, l15, l16);
            acc2[0][tn] = __builtin_amdgcn_mfma_f32_16x16x32_bf16(h1f[kk][0], wf, acc2[0][tn], 0, 0, 0);
            acc2[1][tn] = __builtin_amdgcn_mfma_f32_16x16x32_bf16(h1f[kk][1], wf, acc2[1][tn], 0, 0, 0);
        }
    // H2T[d][k] vector writes: d = tn*16+l15, k = (2w+rr)*16+4*l16+reg -> 8B
    #pragma unroll
    for (int rr = 0; rr < 2; ++rr)
        #pragma unroll
        for (int tn = 0; tn < 4; ++tn) {
            const int d  = tn * 16 + l15;
            const int bo = (2 * w + rr) * 32 + l16 * 8;
            const int addr = d * 256 + (((bo & ~15) ^ ((d & 7) << 4)) | (bo & 15));
            *(uint2*)&Sb[addr] = relu_pk4(acc2[rr][tn]);
        }
    __syncthreads();   // barrier #2: H2T complete (read cross-wave below)

    // ===== P2 (swapped): outT-tile = mfma(H2T-frag, Apk-frag) =====
    f32x4 accO[2][4];
    #pragma unroll
    for (int jj = 0; jj < 2; ++jj)
        #pragma unroll
        for (int dt = 0; dt < 4; ++dt)
            accO[jj][dt] = (f32x4){0.f, 0.f, 0.f, 0.f};

    const unsigned short* Apb = apk + (size_t)b * 32 * 512;
    #pragma unroll
    for (int kk = 0; kk < 4; ++kk) {
        bf16x8 anf[2];
        #pragma unroll
        for (int jj = 0; jj < 2; ++jj) {
            const int jt = 2 * w + jj;
            if (PRE) {
                anf[jj] = *(const bf16x8*)(Apb + (jt * 4 + kk) * 512 + l * 8);
            } else {
                const float4* ap = (const float4*)(A +
                    ((size_t)b * Nv + jt * 16 + l15) * Nv + kk * 32 + 8 * l16);
                anf[jj] = pack8(ap[0], ap[1]);
            }
        }
        #pragma unroll
        for (int dt = 0; dt < 4; ++dt) {
            const int d = dt * 16 + l15;
            const bf16x8 hf = *(const bf16x8*)&Sb[d * 256 + ((kk * 64 + 16 * l16) ^ ((d & 7) << 4))];
            accO[0][dt] = __builtin_amdgcn_mfma_f32_16x16x32_bf16(hf, anf[0], accO[0][dt], 0, 0, 0);
            accO[1][dt] = __builtin_amdgcn_mfma_f32_16x16x32_bf16(hf, anf[1], accO[1][dt], 0, 0, 0);
        }
    }

    // ---- out store: outT tile -> out[j][d]; f32x4 NONTEMPORAL (no L2/L3 alloc) ----
    float* Ob = out + bi * Nv * Dv;
    #pragma unroll
    for (int jj = 0; jj < 2; ++jj) {
        const int j = (2 * w + jj) * 16 + l15;
        const float msk = mask[bi * Nv + j] ? 1.0f : 0.0f;
        float* orow = Ob + (size_t)j * Dv + 4 * l16;
        #pragma unroll
        for (int dt = 0; dt < 4; ++dt) {
            const f32x4 v = accO[jj][dt];
            const f32x4 sv = {v[0] * msk, v[1] * msk, v[2] * msk, v[3] * msk};
            __builtin_nontemporal_store(sv, (f32x4*)&orow[dt * 16]);
        }
    }
}

extern "C" void kernel_launch(void* const* d_in, const int* in_sizes, int n_in,
                              void* d_out, int out_size, void* d_ws, size_t ws_size,
                              hipStream_t stream) {
    const float* X    = (const float*)d_in[0];
    const float* A    = (const float*)d_in[1];
    const int*   mask = (const int*)d_in[2];
    const float* W1   = (const float*)d_in[3];
    const float* b1   = (const float*)d_in[4];
    const float* W2   = (const float*)d_in[5];
    const float* b2   = (const float*)d_in[6];
    float* out = (float*)d_out;

    dim3 grid(Nv, Bv);   // (i, b): blocks sharing b adjacent -> A[b]/apk[b] L2-hot

    if (ws_size >= (size_t)WS_NEED) {
        unsigned char* ws = (unsigned char*)d_ws;
        unsigned short* wpk  = (unsigned short*)ws;
        int*            flag = (int*)(ws + FLAG_OFF_B);
        unsigned short* apk  = (unsigned short*)(ws + APK_OFF_B);
        pack_w_kernel<<<4, 256, 0, stream>>>(W1, W2, wpk);
        pack_a_kernel<<<512, 256, 0, stream>>>(A, apk);
        check_bias<<<1, 128, 0, stream>>>(b1, b2, flag);
        nested_conv_mfma<true><<<grid, 256, 0, stream>>>(
            X, A, mask, W1, b1, W2, b2, wpk, apk, flag, out);
    } else {
        nested_conv_mfma<false><<<grid, 256, 0, stream>>>(
            X, A, mask, W1, b1, W2, b2, nullptr, nullptr, nullptr, out);
    }
}

// Round 17
// 80.328 us; speedup vs baseline: 1.1821x; 1.1821x over previous
//
#include <hip/hip_runtime.h>

// NestedConv via MFMA bf16: B=64, N=128, D=64.
// out[b,i,j,:] = m[b,i,j] * sum_k A[b,k,j] * h[b,i,k,:]
// h = relu(relu((m*X)@W1+b1)@W2+b2),  A symmetric 0/1 (bf16-exact).
//
// Round-17 = Round-12 champion (82.9us) with two pure-overhead deletions:
//  (a) 3 pre-kernels merged into ONE launch (graph replays them serially
//      every iteration: 2 launch overheads saved).
//  (b) barriers 5 -> 2: staging rows (tid>>1), L1 fragment reads, H1 writes,
//      and L2 H1-reads are all within each wave's row band [32w,32w+32) ->
//      same-wave LDS W->R ordering suffices (pattern correctness-proven in
//      R15/R16). Kept: WAR guard before H2T writes + H2T publish barrier.
// Instruction mix otherwise byte-identical to R12.
#define Bv 64
#define Nv 128
#define Dv 64

// ws layout (bytes): [0,16K) wpk; [20480] flag; [32K, 32K+2M) apk.
#define FLAG_OFF_B 20480
#define APK_OFF_B  32768
#define WS_NEED (32768 + Bv * 32768)

typedef __attribute__((ext_vector_type(8))) short bf16x8;
typedef __attribute__((ext_vector_type(4))) float f32x4;

// f32 -> bf16 RNE, pure bit ops
__device__ __forceinline__ unsigned short f2bf(float f) {
    unsigned u = __float_as_uint(f);
    u += 0x7FFFu + ((u >> 16) & 1u);
    return (unsigned short)(u >> 16);
}

// XOR-swizzled byte address in a row-major LDS tile with 128 B rows
__device__ __forceinline__ int swz128(int r, int bi) {
    return r * 128 + (((bi & ~15) ^ ((r & 7) << 4)) | (bi & 15));
}

__device__ __forceinline__ bf16x8 pack8(float4 a, float4 b) {
    bf16x8 r;
    r[0] = (short)f2bf(a.x); r[1] = (short)f2bf(a.y);
    r[2] = (short)f2bf(a.z); r[3] = (short)f2bf(a.w);
    r[4] = (short)f2bf(b.x); r[5] = (short)f2bf(b.y);
    r[6] = (short)f2bf(b.z); r[7] = (short)f2bf(b.w);
    return r;
}

// fallback W fragment loader: 8 strided scalar loads (PRE=false only)
__device__ __forceinline__ bf16x8 load_w_frag(const float* __restrict__ W,
                                              int kkbase, int dn, int l15, int l16) {
    const float* p = W + (kkbase + 8 * l16) * Dv + dn + l15;
    bf16x8 r;
    #pragma unroll
    for (int t = 0; t < 8; ++t) r[t] = (short)f2bf(p[t * Dv]);
    return r;
}

// ---- merged pre-kernel: pack A (blocks 0-511), pack W (512-515), bias check (516) ----
__global__ void pack_all(const float* __restrict__ A,
                         const float* __restrict__ W1,
                         const float* __restrict__ W2,
                         const float* __restrict__ b1,
                         const float* __restrict__ b2,
                         unsigned short* __restrict__ wpk,
                         unsigned short* __restrict__ apk,
                         int* __restrict__ flag) {
    const int blk = blockIdx.x;
    const int tid = threadIdx.x;
    if (blk < 512) {
        // Apk[b][jt][kk][l][t] = A[b][jt*16+(l&15)][kk*32+8*(l>>4)+t]
        const int gid = blk * 256 + tid;                  // 131072 items
        const int l = gid & 63, f = gid >> 6;             // f = b*32 + jt*4 + kk
        const int b = f >> 5, r = f & 31, jt = r >> 2, kk = r & 3;
        const float4* p = (const float4*)(A +
            ((size_t)(b * Nv + jt * 16 + (l & 15))) * Nv + kk * 32 + 8 * (l >> 4));
        *(bf16x8*)(apk + (size_t)f * 512 + l * 8) = pack8(p[0], p[1]);
    } else if (blk < 516) {
        // Wpk[f][l][t], f = layer*8 + kk*4 + tn; value = W[kk*32+8*(l>>4)+t][tn*16+(l&15)]
        const int idx = (blk - 512) * 256 + tid;          // 1024 items
        const int l = idx & 63, f = idx >> 6;
        const int layer = f >> 3, kk = (f >> 2) & 1, tn = f & 3;
        const float* W = layer ? W2 : W1;
        const float* p = W + (kk * 32 + 8 * (l >> 4)) * Dv + tn * 16 + (l & 15);
        unsigned short* o = wpk + f * 512 + l * 8;
        #pragma unroll
        for (int t = 0; t < 8; ++t) o[t] = f2bf(p[t * Dv]);
    } else {
        // flag = 1 iff all biases exactly zero
        __shared__ int nz;
        if (tid == 0) nz = 0;
        __syncthreads();
        if (tid < 128) {
            const float v = (tid < 64) ? b1[tid] : b2[tid - 64];
            if (v != 0.0f) atomicOr(&nz, 1);
        }
        __syncthreads();
        if (tid == 0) flag[0] = (nz == 0) ? 1 : 0;
    }
}

template <bool PRE>
__global__ __launch_bounds__(256, 3)
void nested_conv_mfma(const float* __restrict__ X,
                      const float* __restrict__ A,
                      const int*   __restrict__ mask,
                      const float* __restrict__ W1,
                      const float* __restrict__ b1,
                      const float* __restrict__ W2,
                      const float* __restrict__ b2,
                      const unsigned short* __restrict__ wpk,
                      const unsigned short* __restrict__ apk,
                      const int*   __restrict__ bzflag,
                      float* __restrict__ out)
{
    // One 16 KB buffer, reused: Xs[128][64] -> H1[128][64] -> H2T[64][128] (bf16, swizzled)
    __shared__ __align__(16) unsigned char Sb[16384];

    const int i = blockIdx.x, b = blockIdx.y;
    const int tid = threadIdx.x;
    const int l   = tid & 63;
    const int w   = tid >> 6;       // wave 0..3
    const int l15 = l & 15;
    const int l16 = l >> 4;

    const size_t bi_base = (size_t)(b * Nv + i);
    const int flz = PRE ? bzflag[0] : 0;   // 1 => biases zero => masked rows' X dead

    // ---- stage masked X as bf16 into Xs[r][d] (swizzled; rows tid>>1 are
    //      wave-banded: wave w covers rows [32w, 32w+32)) ----
    {
        const int r    = tid >> 1;
        const int half = (tid & 1) << 5;     // d offset 0 or 32
        const float mm = mask[bi_base * Nv + r] ? 1.0f : 0.0f;
        const float4* xp = (const float4*)(X + (bi_base * Nv + r) * Dv + half);
        if (!flz || mm != 0.0f) {
            #pragma unroll
            for (int g = 0; g < 4; ++g) {
                const float4 v0 = xp[2 * g], v1 = xp[2 * g + 1];
                bf16x8 pk;
                pk[0] = (short)f2bf(mm * v0.x); pk[1] = (short)f2bf(mm * v0.y);
                pk[2] = (short)f2bf(mm * v0.z); pk[3] = (short)f2bf(mm * v0.w);
                pk[4] = (short)f2bf(mm * v1.x); pk[5] = (short)f2bf(mm * v1.y);
                pk[6] = (short)f2bf(mm * v1.z); pk[7] = (short)f2bf(mm * v1.w);
                *(bf16x8*)&Sb[swz128(r, 2 * half + 16 * g)] = pk;
            }
        } else {
            const bf16x8 z = {0, 0, 0, 0, 0, 0, 0, 0};
            #pragma unroll
            for (int g = 0; g < 4; ++g)
                *(bf16x8*)&Sb[swz128(r, 2 * half + 16 * g)] = z;
        }
    }
    // no barrier: L1 reads only this wave's row band (same-wave lgkm ordering)

    f32x4 acc[2][4];

    // ================= layer 1: H1 = relu(Xs @ W1 + b1) =================
    #pragma unroll
    for (int tn = 0; tn < 4; ++tn) {
        const float bv = b1[tn * 16 + l15];
        acc[0][tn] = (f32x4){bv, bv, bv, bv};
        acc[1][tn] = acc[0][tn];
    }
    #pragma unroll
    for (int kk = 0; kk < 2; ++kk) {
        bf16x8 af[2];
        #pragma unroll
        for (int mm = 0; mm < 2; ++mm) {
            const int r = (2 * w + mm) * 16 + l15;
            af[mm] = *(const bf16x8*)&Sb[r * 128 + ((kk * 64 + 16 * l16) ^ ((l15 & 7) << 4))];
        }
        #pragma unroll
        for (int tn = 0; tn < 4; ++tn) {
            const bf16x8 wf = PRE
                ? *(const bf16x8*)(wpk + (0 * 8 + kk * 4 + tn) * 512 + l * 8)
                : load_w_frag(W1, kk * 32, tn * 16, l15, l16);
            acc[0][tn] = __builtin_amdgcn_mfma_f32_16x16x32_bf16(af[0], wf, acc[0][tn], 0, 0, 0);
            acc[1][tn] = __builtin_amdgcn_mfma_f32_16x16x32_bf16(af[1], wf, acc[1][tn], 0, 0, 0);
        }
    }
    // no barrier: H1 writes land in this wave's own row band

    // write H1[r][d] (C-layout: row = tile*16 + 4*l16 + rg, col = tn*16 + l15)
    #pragma unroll
    for (int mm = 0; mm < 2; ++mm)
        #pragma unroll
        for (int tn = 0; tn < 4; ++tn)
            #pragma unroll
            for (int rg = 0; rg < 4; ++rg) {
                const int r = (2 * w + mm) * 16 + 4 * l16 + rg;
                const int d = tn * 16 + l15;
                *(unsigned short*)&Sb[swz128(r, 2 * d)] =
                    f2bf(fmaxf(acc[mm][tn][rg], 0.0f));
            }
    // no barrier: L2 reads only this wave's own H1 band

    // ================= layer 2: H2 = relu(H1 @ W2 + b2) =================
    #pragma unroll
    for (int tn = 0; tn < 4; ++tn) {
        const float bv = b2[tn * 16 + l15];
        acc[0][tn] = (f32x4){bv, bv, bv, bv};
        acc[1][tn] = acc[0][tn];
    }
    #pragma unroll
    for (int kk = 0; kk < 2; ++kk) {
        bf16x8 af[2];
        #pragma unroll
        for (int mm = 0; mm < 2; ++mm) {
            const int r = (2 * w + mm) * 16 + l15;
            af[mm] = *(const bf16x8*)&Sb[r * 128 + ((kk * 64 + 16 * l16) ^ ((l15 & 7) << 4))];
        }
        #pragma unroll
        for (int tn = 0; tn < 4; ++tn) {
            const bf16x8 wf = PRE
                ? *(const bf16x8*)(wpk + (1 * 8 + kk * 4 + tn) * 512 + l * 8)
                : load_w_frag(W2, kk * 32, tn * 16, l15, l16);
            acc[0][tn] = __builtin_amdgcn_mfma_f32_16x16x32_bf16(af[0], wf, acc[0][tn], 0, 0, 0);
            acc[1][tn] = __builtin_amdgcn_mfma_f32_16x16x32_bf16(af[1], wf, acc[1][tn], 0, 0, 0);
        }
    }
    __syncthreads();   // barrier #1 (REQUIRED): all waves' H1 reads done —
                       // H2T writes below touch every wave's band

    // write H2T[d][k] (lane's 4 C-regs are 4 consecutive k at fixed d -> one 8 B write)
    #pragma unroll
    for (int mm = 0; mm < 2; ++mm)
        #pragma unroll
        for (int tn = 0; tn < 4; ++tn) {
            const int d  = tn * 16 + l15;
            const int kb = (2 * w + mm) * 16 + 4 * l16;
            unsigned p0 = (unsigned)f2bf(fmaxf(acc[mm][tn][0], 0.0f))
                        | ((unsigned)f2bf(fmaxf(acc[mm][tn][1], 0.0f)) << 16);
            unsigned p1 = (unsigned)f2bf(fmaxf(acc[mm][tn][2], 0.0f))
                        | ((unsigned)f2bf(fmaxf(acc[mm][tn][3], 0.0f)) << 16);
            const int inrow = 2 * kb;   // multiple of 8
            const int addr  = d * 256 + (((inrow & ~15) ^ ((d & 7) << 4)) | (inrow & 15));
            *(uint2*)&Sb[addr] = make_uint2(p0, p1);
        }
    __syncthreads();   // barrier #2 (REQUIRED): H2T published, read cross-wave

    // ================= phase 2: out[j][d] = sum_k A[b,j,k] * H2[k][d] =================
    f32x4 acc2[2][4];
    #pragma unroll
    for (int jj = 0; jj < 2; ++jj)
        #pragma unroll
        for (int td = 0; td < 4; ++td)
            acc2[jj][td] = (f32x4){0.f, 0.f, 0.f, 0.f};

    const float* Ab = A + (size_t)b * Nv * Nv;
    const unsigned short* Apb = apk + (size_t)b * 32 * 512;
    #pragma unroll
    for (int kk = 0; kk < 4; ++kk) {
        bf16x8 af[2];
        #pragma unroll
        for (int jj = 0; jj < 2; ++jj) {
            const int jt = 2 * w + jj;
            if (PRE) {
                af[jj] = *(const bf16x8*)(Apb + (jt * 4 + kk) * 512 + l * 8);
            } else {
                const float4* ap = (const float4*)(Ab + (size_t)(jt * 16 + l15) * Nv + kk * 32 + 8 * l16);
                af[jj] = pack8(ap[0], ap[1]);
            }
        }
        #pragma unroll
        for (int td = 0; td < 4; ++td) {
            const int d = td * 16 + l15;
            const bf16x8 bfr = *(const bf16x8*)&Sb[d * 256 + ((kk * 64 + 16 * l16) ^ ((l15 & 7) << 4))];
            acc2[0][td] = __builtin_amdgcn_mfma_f32_16x16x32_bf16(af[0], bfr, acc2[0][td], 0, 0, 0);
            acc2[1][td] = __builtin_amdgcn_mfma_f32_16x16x32_bf16(af[1], bfr, acc2[1][td], 0, 0, 0);
        }
    }

    // ---- masked store (NONTEMPORAL scalar: champion R12 pattern) ----
    const int*  mrow  = mask + bi_base * Nv;
    float*      Obase = out + bi_base * Nv * Dv;
    #pragma unroll
    for (int jj = 0; jj < 2; ++jj)
        #pragma unroll
        for (int rg = 0; rg < 4; ++rg) {
            const int j = (2 * w + jj) * 16 + 4 * l16 + rg;
            const float msk = mrow[j] ? 1.0f : 0.0f;
            float* orow = Obase + (size_t)j * Dv + l15;
            #pragma unroll
            for (int td = 0; td < 4; ++td)
                __builtin_nontemporal_store(acc2[jj][td][rg] * msk, &orow[td * 16]);
        }
}

extern "C" void kernel_launch(void* const* d_in, const int* in_sizes, int n_in,
                              void* d_out, int out_size, void* d_ws, size_t ws_size,
                              hipStream_t stream) {
    const float* X    = (const float*)d_in[0];
    const float* A    = (const float*)d_in[1];
    const int*   mask = (const int*)d_in[2];
    const float* W1   = (const float*)d_in[3];
    const float* b1   = (const float*)d_in[4];
    const float* W2   = (const float*)d_in[5];
    const float* b2   = (const float*)d_in[6];
    float* out = (float*)d_out;

    dim3 grid(Nv, Bv);   // (i, b): blocks sharing b are adjacent -> A[b] L2-hot

    if (ws_size >= (size_t)WS_NEED) {
        unsigned char* ws = (unsigned char*)d_ws;
        unsigned short* wpk  = (unsigned short*)ws;
        int*            flag = (int*)(ws + FLAG_OFF_B);
        unsigned short* apk  = (unsigned short*)(ws + APK_OFF_B);
        pack_all<<<517, 256, 0, stream>>>(A, W1, W2, b1, b2, wpk, apk, flag);
        nested_conv_mfma<true><<<grid, 256, 0, stream>>>(
            X, A, mask, W1, b1, W2, b2, wpk, apk, flag, out);
    } else {
        nested_conv_mfma<false><<<grid, 256, 0, stream>>>(
            X, A, mask, W1, b1, W2, b2, nullptr, nullptr, nullptr, out);
    }
}